// Round 6
// baseline (163.228 us; speedup 1.0000x reference)
//
#include <hip/hip_runtime.h>

// RelativePositionEncoding, N=1024, C=128, 512 MiB f32 write-stream.
// R1/R3/R4/R5 all ~115us (4.66 TB/s) regardless of structure; fill = 6.7 TB/s.
// Last hypothesis: stores are gated by per-iteration load dependencies.
// This version: steady-state inner loop has ZERO memory reads on the store's
// dependence chain for the dominant cross-chain path. Each thread's 32 j-token
// features live in registers (packed at startup; j-set independent of i).
//   mpack[k] = r | t<<9 | a<<19 | e<<22   (ranges 512/1024/8/4 -> 24 bits)
//   mval[k]  = mask[j]
// Same-chain (~12.5%): 2 LDS row reads (table in LDS, 71 KB).

#define N_TOK  1024
#define C_PAIR 128
#define NR     66
#define W_COLS 139

typedef float f32x4 __attribute__((ext_vector_type(4)));

__global__ __launch_bounds__(1024)
void relpos_kernel(const int* __restrict__ ri, const int* __restrict__ ti,
                   const int* __restrict__ ai, const int* __restrict__ ei,
                   const float* __restrict__ mask, const float* __restrict__ W,
                   float* __restrict__ out) {
    __shared__ float wt[W_COLS * C_PAIR];   // wt[k][c] = W[c][k]; 71.2 KB

    const int c4 = threadIdx.x & 31;        // f32x4 channel slot (0..31)
    const int jg = threadIdx.x >> 5;        // j base group (0..31)

    // Register-resident features for this thread's j-set (j = jg + 32k).
    // Fully unrolled -> static indices -> registers, not scratch.
    int   mpack[32];
    float mval[32];
    #pragma unroll
    for (int k = 0; k < 32; ++k) {
        int j = jg + 32 * k;
        mpack[k] = (ri[j] & 511) | ((ti[j] & 1023) << 9)
                 | ((ai[j] & 7) << 19) | ((ei[j] & 3) << 22);
        mval[k]  = mask[j];
    }

    // Stage transposed W in LDS (coalesced read, startup only).
    for (int idx = threadIdx.x; idx < C_PAIR * W_COLS; idx += blockDim.x) {
        int c = idx / W_COLS;
        int k = idx - c * W_COLS;
        wt[k * C_PAIR + c] = W[idx];
    }
    __syncthreads();

    const f32x4* wt4 = (const f32x4*)wt;
    const f32x4 went  = wt4[132 * 32 + c4];                 // Went
    const f32x4 wc2   = wt4[135 * 32 + c4];                 // Wchain[2] (same-chain)
    const f32x4 sdiff = wt4[65 * 32 + c4] + wt4[131 * 32 + c4]
                      + wt4[138 * 32 + c4];                 // cross-chain const

    for (int i = blockIdx.x; i < N_TOK; i += gridDim.x) {
        const int   r_i = ri[i], t_i = ti[i], a_i = ai[i], e_i = ei[i];
        const float m_i = mask[i];
        f32x4* __restrict__ orow = (f32x4*)(out + (size_t)i * (N_TOK * C_PAIR));

        #pragma unroll
        for (int k = 0; k < 32; ++k) {
            int mp  = mpack[k];
            int r_j = mp & 511;
            int t_j = (mp >> 9) & 1023;
            int a_j = (mp >> 19) & 7;
            int e_j = mp >> 22;
            float mm = m_i * mval[k];
            float f  = (e_i == e_j) ? 1.0f : 0.0f;

            f32x4 v;
            if (a_i == a_j) {    // same chain (~12.5%), 2 LDS row reads
                int dp = min(max(r_j - r_i + 32, 0), 64);
                int r2 = (r_i == r_j) ? (NR + min(max(t_j - t_i + 32, 0), 64))
                                      : 131;                // Wtok[65]
                v = wt4[dp * 32 + c4] + wt4[r2 * 32 + c4] + wc2;
            } else {             // cross chain (~87.5%): registers only
                v = sdiff;
            }
            v = (v + f * went) * mm;
            orow[(jg + 32 * k) * 32 + c4] = v;   // wave: 1 KB contiguous
        }
    }
}

extern "C" void kernel_launch(void* const* d_in, const int* in_sizes, int n_in,
                              void* d_out, int out_size, void* d_ws, size_t ws_size,
                              hipStream_t stream) {
    const int*   ri   = (const int*)d_in[0];
    const int*   ti   = (const int*)d_in[1];
    const int*   ai   = (const int*)d_in[2];
    const int*   ei   = (const int*)d_in[3];
    const float* mask = (const float*)d_in[4];
    const float* W    = (const float*)d_in[5];
    float*       out  = (float*)d_out;

    relpos_kernel<<<512, 1024, 0, stream>>>(ri, ti, ai, ei, mask, W, out);
}

// Round 8
// 125.456 us; speedup vs baseline: 1.3011x; 1.3011x over previous
//
#include <hip/hip_runtime.h>

// RelativePositionEncoding, N=1024, C=128, 512 MiB f32 write-stream.
// Evidence R1-R7: ~115us across all structures; fit vs harness fill gives
// B~7.85 TB/s + fixed ~46us dispatch overhead => likely already saturated.
// This round: R7's load-free-store structure with PLAIN stores (R7's
// sc0sc1nt stores broke readback coherence with harness L2 state).
// Per iteration: 1 ds_read_b64 (i-features broadcast) + VALU + 1 store.
// j-features/channel slices are loop-invariant registers.

#define N_TOK  1024
#define C_PAIR 128
#define NR     66
#define W_COLS 139

typedef float f32x4 __attribute__((ext_vector_type(4)));

// g_wt[k][c]: k<139 = W[c][k] (transposed W); row 139 = W[c][65]+W[c][131]
// (= Wpos[65]+Wtok[65], the reference's first add -> bit-exact grouping).
__device__ f32x4 g_wt[140 * 32];
__device__ uint2 g_fm[N_TOK];     // .x = r|t<<9|a<<19|e<<22, .y = mask bits

__global__ __launch_bounds__(256)
void prep_kernel(const int* __restrict__ ri, const int* __restrict__ ti,
                 const int* __restrict__ ai, const int* __restrict__ ei,
                 const float* __restrict__ mask, const float* __restrict__ W) {
    int t = blockIdx.x * blockDim.x + threadIdx.x;
    int stride = gridDim.x * blockDim.x;
    float* wt = (float*)g_wt;
    for (int idx = t; idx < 139 * C_PAIR; idx += stride) {
        int k = idx >> 7, c = idx & 127;
        wt[k * C_PAIR + c] = W[c * W_COLS + k];
    }
    for (int c = t; c < C_PAIR; c += stride)
        wt[139 * C_PAIR + c] = W[c * W_COLS + 65] + W[c * W_COLS + 131];
    for (int j = t; j < N_TOK; j += stride) {
        uint2 p;
        p.x = (unsigned)(ri[j] & 511) | ((unsigned)(ti[j] & 1023) << 9)
            | ((unsigned)(ai[j] & 7) << 19) | ((unsigned)(ei[j] & 3) << 22);
        p.y = __float_as_uint(mask[j]);
        g_fm[j] = p;
    }
}

__device__ __forceinline__ int clamp64(int x) { return min(max(x, 0), 64); }

__global__ __launch_bounds__(256)
void relpos_kernel(float* __restrict__ out) {
    __shared__ uint2 sfm[N_TOK];                  // 8 KB
    for (int idx = threadIdx.x; idx < N_TOK; idx += 256)
        sfm[idx] = g_fm[idx];

    const int g0 = blockIdx.x * 256 + threadIdx.x;
    const int c4 = g0 & 31;                       // channel slot, loop-invariant
    const int j  = (g0 >> 5) & (N_TOK - 1);       // invariant: stride>>5 % 1024 == 0

    // Register-cached table slices (20 VGPRs).
    const f32x4 s_pt = g_wt[139 * 32 + c4];       // Wpos[65]+Wtok[65]
    const f32x4 went = g_wt[132 * 32 + c4];       // Went
    const f32x4 ch5  = g_wt[138 * 32 + c4];       // Wchain[5] (cross-chain)
    const f32x4 ch2  = g_wt[135 * 32 + c4];       // Wchain[2] (same-chain)
    __syncthreads();

    const uint2 fmj = sfm[j];
    const int r_j = fmj.x & 511;
    const int t_j = (fmj.x >> 9) & 1023;
    const int a_j = (fmj.x >> 19) & 7;
    const int e_j = fmj.x >> 22;
    const float mj = __uint_as_float(fmj.y);

    const int total  = N_TOK * N_TOK * 32;        // f32x4 items
    const int stride = 2048 * 256;                // grid size; preserves invariance
    f32x4* __restrict__ out4 = (f32x4*)out;

    #pragma unroll 4
    for (int g = g0; g < total; g += stride) {
        int i = g >> 15;
        uint2 fmi = sfm[i];                       // one ds_read_b64, broadcast
        float mm = __uint_as_float(fmi.y) * mj;
        float f  = ((int)(fmi.x >> 22) == e_j) ? 1.0f : 0.0f;

        f32x4 v;
        if ((int)((fmi.x >> 19) & 7) == a_j) {    // same chain (~12.5%)
            int r_i = fmi.x & 511;
            int dp  = clamp64(r_j - r_i + 32);
            int row2 = (r_i == r_j)
                     ? (NR + clamp64(t_j - (int)((fmi.x >> 9) & 1023) + 32))
                     : 131;                        // Wtok[65]
            v = ((g_wt[dp * 32 + c4] + g_wt[row2 * 32 + c4]) + f * went) + ch2;
        } else {                                   // cross chain (~87.5%): VALU only
            v = (s_pt + f * went) + ch5;
        }
        out4[g] = v * mm;                          // plain store; wave: 1 KB contig
    }
}

extern "C" void kernel_launch(void* const* d_in, const int* in_sizes, int n_in,
                              void* d_out, int out_size, void* d_ws, size_t ws_size,
                              hipStream_t stream) {
    const int*   ri   = (const int*)d_in[0];
    const int*   ti   = (const int*)d_in[1];
    const int*   ai   = (const int*)d_in[2];
    const int*   ei   = (const int*)d_in[3];
    const float* mask = (const float*)d_in[4];
    const float* W    = (const float*)d_in[5];
    float*       out  = (float*)d_out;

    prep_kernel<<<64, 256, 0, stream>>>(ri, ti, ai, ei, mask, W);   // parallel, ~3 us
    relpos_kernel<<<2048, 256, 0, stream>>>(out);                   // 64 iters/thread
}

// Round 9
// 115.081 us; speedup vs baseline: 1.4184x; 1.0902x over previous
//
#include <hip/hip_runtime.h>

// RelativePositionEncoding: out[i,j,c] = (Wpos[dp,c] + Wtok[dt,c]
//   + same_ent*Went[c] + Wchain[dc,c]) * mask[i]*mask[j]
// N=1024, C=128. Pure write-stream (512 MiB f32). Table (140x128 f32,
// 71.7 KB incl. zero row) staged in LDS. Each thread computes its pair's
// buckets ONCE and emits 64 B (4x float4) via non-temporal stores.
// R1-R8 evidence: time is pinned at ~115us across five structure classes
// (work/LDS/flags/shape/dependence all varied) => bytes/7.85TB/s + ~46us
// fixed overhead floor. This is the best-measured variant (R3: 115.1us).

#define N_TOK 1024
#define C_PAIR 128
#define NR 66            // 2*R_MAX + 2
#define NS 6             // 2*S_MAX + 2
#define W_COLS 139       // 2*NR + NS + 1
#define ROWS 140         // 139 + one zero row (same_entity==false)

typedef float f32x4 __attribute__((ext_vector_type(4)));   // native vec for nt-store

__global__ __launch_bounds__(1024, 8)
void relpos_kernel(const int* __restrict__ ri, const int* __restrict__ ti,
                   const int* __restrict__ ai, const int* __restrict__ ei,
                   const float* __restrict__ mask, const float* __restrict__ W,
                   float* __restrict__ out) {
    __shared__ float wt[ROWS * C_PAIR];  // wt[k][c] = W[c][k]; row 139 = zeros

    // Coalesced read of W [128][139]; transposed write into LDS (startup only).
    for (int idx = threadIdx.x; idx < C_PAIR * W_COLS; idx += blockDim.x) {
        int c = idx / W_COLS;            // compiler magic-mul
        int k = idx - c * W_COLS;
        wt[k * C_PAIR + c] = W[idx];
    }
    for (int idx = threadIdx.x; idx < C_PAIR; idx += blockDim.x)
        wt[(ROWS - 1) * C_PAIR + idx] = 0.0f;
    __syncthreads();

    const int total  = N_TOK * N_TOK * 8;          // 64-B items = 8,388,608
    const int stride = gridDim.x * blockDim.x;     // 524,288 -> 16 iters/thread
    f32x4* __restrict__ out4 = (f32x4*)out;

    for (int t = blockIdx.x * blockDim.x + threadIdx.x; t < total; t += stride) {
        int c4   = t & 7;                // base float4 slot; writes c4+{0,8,16,24}
        int pair = t >> 3;
        int j = pair & (N_TOK - 1);
        int i = pair >> 10;

        // 8-lane groups share (i,j) -> <=8 distinct addrs/wave, L1-resident.
        int   r_i = ri[i], r_j = ri[j];
        int   t_i = ti[i], t_j = ti[j];
        int   a_i = ai[i], a_j = ai[j];
        int   e_i = ei[i], e_j = ei[j];
        float m   = mask[i] * mask[j];

        bool same_chain = (a_i == a_j);
        bool same_res   = (r_i == r_j);

        // d[i,j] = feat[j] - feat[i]
        int dp = same_chain               ? min(max(r_j - r_i + 32, 0), 64) : 65;
        int dt = (same_chain && same_res) ? min(max(t_j - t_i + 32, 0), 64) : 65;
        int dc = same_chain               ? min(max(a_j - a_i + 2,  0), 4)  : 5;
        int re = (e_i == e_j) ? (2 * NR) : (ROWS - 1);   // 132 or zero row

        const f32x4* wp = (const f32x4*)&wt[dp * C_PAIR];
        const f32x4* wk = (const f32x4*)&wt[(NR + dt) * C_PAIR];
        const f32x4* we = (const f32x4*)&wt[re * C_PAIR];
        const f32x4* wc = (const f32x4*)&wt[(2 * NR + 1 + dc) * C_PAIR];

        int base = pair * 32 + c4;
        #pragma unroll
        for (int q = 0; q < 4; ++q) {
            int cc = c4 + 8 * q;
            f32x4 v = (wp[cc] + wk[cc] + we[cc] + wc[cc]) * m;
            __builtin_nontemporal_store(v, &out4[base + 8 * q]);
        }
    }
}

extern "C" void kernel_launch(void* const* d_in, const int* in_sizes, int n_in,
                              void* d_out, int out_size, void* d_ws, size_t ws_size,
                              hipStream_t stream) {
    const int*   ri   = (const int*)d_in[0];
    const int*   ti   = (const int*)d_in[1];
    const int*   ai   = (const int*)d_in[2];
    const int*   ei   = (const int*)d_in[3];
    const float* mask = (const float*)d_in[4];
    const float* W    = (const float*)d_in[5];
    float*       out  = (float*)d_out;

    const int threads = 1024;
    const int blocks  = 512;   // 2 blocks/CU (71.7 KB LDS), 16 iters/thread
    relpos_kernel<<<blocks, threads, 0, stream>>>(ri, ti, ai, ei, mask, W, out);
}